// Round 3
// baseline (685.867 us; speedup 1.0000x reference)
//
#include <hip/hip_runtime.h>
#include <math.h>

#define LL 2
#define BB 32
#define SS 2048
#define HH 512
#define DD 1024      // 2*H
#define W4S 2048     // attn_w row stride = 4*H

typedef __attribute__((ext_vector_type(8))) short bf16x8;
typedef __attribute__((ext_vector_type(4))) float f32x4;

// fp32 pair -> packed bf16x2, round-to-nearest-even (used in one-time pack)
__device__ inline unsigned pk2_rne(float a, float b) {
    unsigned ua = __float_as_uint(a), ub = __float_as_uint(b);
    unsigned ra = (ua + 0x7fffu + ((ua >> 16) & 1u)) >> 16;
    unsigned rb = (ub + 0x7fffu + ((ub >> 16) & 1u)) & 0xffff0000u;
    return ra | rb;
}

// fp32 pair -> packed bf16x2, round-half-up: add 0x8000, take high halves.
// 3 VALU ops (add, add, v_perm). Bias ~2^-17 relative — fine vs 2.6e-3 thresh.
__device__ inline unsigned pk2_hu(float a, float b) {
    unsigned ua = __float_as_uint(a) + 0x8000u;
    unsigned ub = __float_as_uint(b) + 0x8000u;
    // result bytes [3:0] = [ub.b3 ub.b2 ua.b3 ua.b2]
    return __builtin_amdgcn_perm(ub, ua, 0x07060302u);
}

__device__ inline float fast_tanh(float x) {
    x = fminf(9.f, fmaxf(-9.f, x));
    float e = __expf(2.f * x);
    return 1.f - 2.f * __builtin_amdgcn_rcpf(e + 1.f);
}

// ---------------- zero init (scores ws + context out get atomics) -------------
__global__ void k_zero(float* __restrict__ scores, float* __restrict__ ctx) {
    int i = blockIdx.x * 256 + threadIdx.x;   // grid covers BB*SS
    scores[i] = 0.f;
    if (i < BB * DD) ctx[i] = 0.f;
}

// ---------------- one-time pack: w_e fp32 -> bf16 row-major [HH][DD] ---------
__global__ __launch_bounds__(256) void k_pack(const float* __restrict__ attn_w,
                                              unsigned short* __restrict__ Bp) {
    int h = blockIdx.x, t = threadIdx.x;
    float4 v = *(const float4*)(attn_w + (size_t)h * W4S + DD + t * 4);
    uint2 r = make_uint2(pk2_rne(v.x, v.y), pk2_rne(v.z, v.w));
    *(uint2*)(Bp + (size_t)h * DD + t * 4) = r;
}

// ---------------- base[b,h] = dot(hidden[-1,b,:], w_h[h,:]) + bias[h] --------
__global__ __launch_bounds__(256) void k_base(const float* __restrict__ hidden,
                                              const float* __restrict__ attn_w,
                                              const float* __restrict__ attn_b,
                                              float* __restrict__ base) {
    int wid  = (blockIdx.x * 256 + threadIdx.x) >> 6;   // one wave per (b,h)
    int lane = threadIdx.x & 63;
    int b = wid >> 9;          // / HH
    int h = wid & (HH - 1);
    const float4* h4 = (const float4*)(hidden + (size_t)(LL - 1) * BB * DD + (size_t)b * DD);
    const float4* w4 = (const float4*)(attn_w + (size_t)h * W4S);   // w_h
    float s = 0.f;
    #pragma unroll
    for (int i = 0; i < 4; i++) {
        float4 a = h4[lane + i * 64], w = w4[lane + i * 64];
        s += a.x * w.x + a.y * w.y + a.z * w.z + a.w * w.w;
    }
    #pragma unroll
    for (int off = 32; off; off >>= 1) s += __shfl_xor(s, off);
    if (lane == 0) base[b * HH + h] = s + attn_b[h];
}

// ---------------- big GEMM (bf16 MFMA, no LDS, no barriers) ------------------
// C[m,n] = sum_k enc[m,k] * w_e[n,k];  scores[m] += sum_n tanh(C+base)*v
// Per wave: 64m x 64n tile = 4x4 MFMA frags. A frags loaded k-contiguous from
// enc (fp32 -> bf16 in-register); B frags direct bf16x8 loads from packed Bp
// (1 MB, L2-resident). No __syncthreads in the K-loop.
__global__ __launch_bounds__(256) void k_scores(const float* __restrict__ enc,
                                                const unsigned short* __restrict__ Bp,
                                                const float* __restrict__ base,
                                                const float* __restrict__ vw,
                                                float* __restrict__ scores) {
    const int tid  = threadIdx.x;
    const int wid  = tid >> 6;
    const int lane = tid & 63;
    const int lm   = lane & 15;
    const int kq   = lane >> 4;                // 0..3
    const int n0   = blockIdx.x * 256;         // 0 or 256
    const int m0   = blockIdx.y * 64;
    const int b    = m0 >> 11;                 // 64 | 2048 -> uniform per block
    const int wn   = n0 + wid * 64;            // wave's absolute n-slice base

    // lane base pointers: A row m0+lm (+ mi*16 rows), col kq*8; B row wn+lm
    const float*          Ap = enc + (size_t)(m0 + lm) * DD + kq * 8;
    const unsigned short* Bq = Bp  + (size_t)(wn + lm) * DD + kq * 8;

    f32x4 acc[4][4];
    #pragma unroll
    for (int i = 0; i < 4; i++)
        #pragma unroll
        for (int j = 0; j < 4; j++) acc[i][j] = (f32x4){0.f, 0.f, 0.f, 0.f};

    #pragma unroll 2
    for (int kt = 0; kt < DD; kt += 32) {
        bf16x8 af[4];
        #pragma unroll
        for (int mi = 0; mi < 4; mi++) {
            float4 x = *(const float4*)(Ap + (size_t)mi * 16 * DD + kt);
            float4 y = *(const float4*)(Ap + (size_t)mi * 16 * DD + kt + 4);
            union { unsigned u[4]; bf16x8 v; } c;
            c.u[0] = pk2_hu(x.x, x.y); c.u[1] = pk2_hu(x.z, x.w);
            c.u[2] = pk2_hu(y.x, y.y); c.u[3] = pk2_hu(y.z, y.w);
            af[mi] = c.v;
        }
        #pragma unroll
        for (int ni = 0; ni < 4; ni++) {
            bf16x8 bf = *(const bf16x8*)(Bq + (size_t)ni * 16 * DD + kt);
            #pragma unroll
            for (int mi = 0; mi < 4; mi++)
                acc[mi][ni] = __builtin_amdgcn_mfma_f32_16x16x32_bf16(
                    af[mi], bf, acc[mi][ni], 0, 0, 0);
        }
    }

    // epilogue: p[mi][r] = sum over this wave's 64 cols of tanh(C+base)*v
    const float* basep = base + b * HH + wn;
    const float* vp    = vw + wn;
    float p[4][4] = {};
    #pragma unroll
    for (int ni = 0; ni < 4; ni++) {
        int nl = ni * 16 + lm;
        float bs = basep[nl];
        float vv = vp[nl];
        #pragma unroll
        for (int mi = 0; mi < 4; mi++)
            #pragma unroll
            for (int r = 0; r < 4; r++)
                p[mi][r] += vv * fast_tanh(acc[mi][ni][r] + bs);
    }
    #pragma unroll
    for (int off = 8; off; off >>= 1)
        #pragma unroll
        for (int mi = 0; mi < 4; mi++)
            #pragma unroll
            for (int r = 0; r < 4; r++)
                p[mi][r] += __shfl_xor(p[mi][r], off);
    if (lm == 0) {
        #pragma unroll
        for (int mi = 0; mi < 4; mi++)
            #pragma unroll
            for (int r = 0; r < 4; r++)
                atomicAdd(&scores[m0 + mi * 16 + kq * 4 + r], p[mi][r]);
    }
}

// ---------------- softmax over S per batch -----------------------------------
__global__ __launch_bounds__(256) void k_softmax(const float* __restrict__ scores,
                                                 float* __restrict__ wout) {
    int b = blockIdx.x, tid = threadIdx.x;
    const float* rowp = scores + b * SS;
    float v[8];
    float m = -1e30f;
    #pragma unroll
    for (int i = 0; i < 8; i++) { v[i] = rowp[tid + i * 256]; m = fmaxf(m, v[i]); }
    __shared__ float sm[4], ssum[4];
    #pragma unroll
    for (int off = 32; off; off >>= 1) m = fmaxf(m, __shfl_xor(m, off));
    if ((tid & 63) == 0) sm[tid >> 6] = m;
    __syncthreads();
    m = fmaxf(fmaxf(sm[0], sm[1]), fmaxf(sm[2], sm[3]));
    float s = 0.f;
    #pragma unroll
    for (int i = 0; i < 8; i++) { v[i] = __expf(v[i] - m); s += v[i]; }
    #pragma unroll
    for (int off = 32; off; off >>= 1) s += __shfl_xor(s, off);
    if ((tid & 63) == 0) ssum[tid >> 6] = s;
    __syncthreads();
    s = ssum[0] + ssum[1] + ssum[2] + ssum[3];
    float inv = 1.f / s;
    #pragma unroll
    for (int i = 0; i < 8; i++) wout[b * SS + tid + i * 256] = v[i] * inv;
}

// ---------------- context[b,d] = sum_s w[b,s]*enc[b,s,d] ---------------------
#define CCH 64
__global__ __launch_bounds__(256) void k_context(const float* __restrict__ enc,
                                                 const float* __restrict__ w,
                                                 float* __restrict__ ctx) {
    int b = blockIdx.x, chunk = blockIdx.y, tid = threadIdx.x;
    __shared__ float wsh[CCH];
    int s0 = chunk * CCH;
    if (tid < CCH) wsh[tid] = w[b * SS + s0 + tid];
    __syncthreads();
    const float4* e4 = (const float4*)(enc + (size_t)b * SS * DD);
    float4 acc = {0.f, 0.f, 0.f, 0.f};
    #pragma unroll 8
    for (int s = 0; s < CCH; s++) {
        float wv  = wsh[s];
        float4 ev = e4[(size_t)(s0 + s) * (DD / 4) + tid];
        acc.x += wv * ev.x; acc.y += wv * ev.y;
        acc.z += wv * ev.z; acc.w += wv * ev.w;
    }
    float* c = ctx + b * DD + tid * 4;
    atomicAdd(c + 0, acc.x); atomicAdd(c + 1, acc.y);
    atomicAdd(c + 2, acc.z); atomicAdd(c + 3, acc.w);
}

extern "C" void kernel_launch(void* const* d_in, const int* in_sizes, int n_in,
                              void* d_out, int out_size, void* d_ws, size_t ws_size,
                              hipStream_t stream) {
    const float* hidden = (const float*)d_in[0];   // (L,B,D)
    const float* enc    = (const float*)d_in[1];   // (B,S,D)
    const float* attn_w = (const float*)d_in[2];   // (H,4H)
    const float* attn_b = (const float*)d_in[3];   // (H,)
    const float* v_w    = (const float*)d_in[4];   // (1,H)

    float* out      = (float*)d_out;
    float* ctx_out  = out;               // (B,1,D) flat = B*D
    float* attn_out = out + BB * DD;     // (B,1,S) flat = B*S

    float* base   = (float*)d_ws;                    // B*H floats
    float* scores = base + BB * HH;                  // B*S floats
    unsigned short* Bp = (unsigned short*)(scores + BB * SS);  // H*D bf16 = 1 MB

    hipLaunchKernelGGL(k_zero, dim3(BB * SS / 256), dim3(256), 0, stream,
                       scores, ctx_out);
    hipLaunchKernelGGL(k_pack, dim3(HH), dim3(256), 0, stream,
                       attn_w, Bp);
    hipLaunchKernelGGL(k_base, dim3(BB * HH / 4), dim3(256), 0, stream,
                       hidden, attn_w, attn_b, base);
    hipLaunchKernelGGL(k_scores, dim3(2, BB * SS / 64), dim3(256), 0, stream,
                       enc, Bp, base, v_w, scores);
    hipLaunchKernelGGL(k_softmax, dim3(BB), dim3(256), 0, stream,
                       scores, attn_out);
    hipLaunchKernelGGL(k_context, dim3(BB, SS / CCH), dim3(256), 0, stream,
                       enc, attn_out, ctx_out);
}

// Round 4
// 478.745 us; speedup vs baseline: 1.4326x; 1.4326x over previous
//
#include <hip/hip_runtime.h>
#include <math.h>

#define LL 2
#define BB 32
#define SS 2048
#define HH 512
#define DD 1024      // 2*H
#define W4S 2048     // attn_w row stride = 4*H

// k_scores tiling
#define BM 64
#define BN 256
#define BK 64
#define NT (DD / BK)     // 16 k-tiles
#define ASTR 72          // A LDS row stride in shorts (144 B = 9*16, 16B-aligned granules)

typedef __attribute__((ext_vector_type(8))) short bf16x8;
typedef __attribute__((ext_vector_type(4))) float f32x4;

// fp32 pair -> packed bf16x2, round-to-nearest-even (one-time pack)
__device__ inline unsigned pk2_rne(float a, float b) {
    unsigned ua = __float_as_uint(a), ub = __float_as_uint(b);
    unsigned ra = (ua + 0x7fffu + ((ua >> 16) & 1u)) >> 16;
    unsigned rb = (ub + 0x7fffu + ((ub >> 16) & 1u)) & 0xffff0000u;
    return ra | rb;
}

// fp32 pair -> packed bf16x2, round-half-up: 2 adds + v_perm
__device__ inline unsigned pk2_hu(float a, float b) {
    unsigned ua = __float_as_uint(a) + 0x8000u;
    unsigned ub = __float_as_uint(b) + 0x8000u;
    return __builtin_amdgcn_perm(ub, ua, 0x07060302u);
}

__device__ inline float fast_tanh(float x) {
    x = fminf(9.f, fmaxf(-9.f, x));
    float e = __expf(2.f * x);
    return 1.f - 2.f * __builtin_amdgcn_rcpf(e + 1.f);
}

// async global->LDS, 16 B per lane; LDS dest = base + lane*16
__device__ inline void gl_lds16(const unsigned short* g, short* l) {
    __builtin_amdgcn_global_load_lds(
        (const __attribute__((address_space(1))) unsigned int*)g,
        (__attribute__((address_space(3))) unsigned int*)l, 16, 0, 0);
}

// ---------------- zero scores (atomic target) --------------------------------
__global__ void k_zero(float* __restrict__ scores) {
    scores[blockIdx.x * 256 + threadIdx.x] = 0.f;
}

// ---------------- one-time pack: w_e fp32 -> bf16 row-major [HH][DD] ---------
__global__ __launch_bounds__(256) void k_pack(const float* __restrict__ attn_w,
                                              unsigned short* __restrict__ Bp) {
    int h = blockIdx.x, t = threadIdx.x;
    float4 v = *(const float4*)(attn_w + (size_t)h * W4S + DD + t * 4);
    uint2 r = make_uint2(pk2_rne(v.x, v.y), pk2_rne(v.z, v.w));
    *(uint2*)(Bp + (size_t)h * DD + t * 4) = r;
}

// ---------------- base[b,h] = dot(hidden[-1,b,:], w_h[h,:]) + bias[h] --------
__global__ __launch_bounds__(256) void k_base(const float* __restrict__ hidden,
                                              const float* __restrict__ attn_w,
                                              const float* __restrict__ attn_b,
                                              float* __restrict__ base) {
    int wid  = (blockIdx.x * 256 + threadIdx.x) >> 6;
    int lane = threadIdx.x & 63;
    int b = wid >> 9;
    int h = wid & (HH - 1);
    const float4* h4 = (const float4*)(hidden + (size_t)(LL - 1) * BB * DD + (size_t)b * DD);
    const float4* w4 = (const float4*)(attn_w + (size_t)h * W4S);
    float s = 0.f;
    #pragma unroll
    for (int i = 0; i < 4; i++) {
        float4 a = h4[lane + i * 64], w = w4[lane + i * 64];
        s += a.x * w.x + a.y * w.y + a.z * w.z + a.w * w.w;
    }
    #pragma unroll
    for (int off = 32; off; off >>= 1) s += __shfl_xor(s, off);
    if (lane == 0) base[b * HH + h] = s + attn_b[h];
}

// ---------------- big GEMM (bf16 MFMA, LDS staged, B double-buffered) --------
// C[m,n] = sum_k enc[m,k]*w_e[n,k]; scores[m] += sum_n tanh(C+base)*v
__global__ __launch_bounds__(256, 2) void k_scores(const float* __restrict__ enc,
                                                   const unsigned short* __restrict__ Bp,
                                                   const float* __restrict__ base,
                                                   const float* __restrict__ vw,
                                                   float* __restrict__ scores) {
    __shared__ short As[BM * ASTR];     // 9216 B, padded rows (2-way banks max)
    __shared__ short Bs[2][BN * BK];    // 2 x 32 KB, granule-XOR swizzled

    const int tid  = threadIdx.x;
    const int wid  = tid >> 6;
    const int lane = tid & 63;
    const int lm   = lane & 15;
    const int kq   = lane >> 4;
    const int n0   = blockIdx.x * BN;          // 0 or 256
    const int m0   = blockIdx.y * BM;
    const int b    = m0 >> 11;
    const int wn   = wid * 64;                 // wave's n-slice inside BN

    // A staging: thread handles bf16 granules t and t+256 -> rows t>>3, t>>3+32
    const int rowA = tid >> 3;                 // 0..31
    const int gA   = tid & 7;                  // granule col (16 B = 8 bf16 = 8 fp32/32 B)
    const float* Ag0 = enc + (size_t)(m0 + rowA) * DD + gA * 8;
    const float* Ag1 = Ag0 + (size_t)32 * DD;
    short* AsW0 = As + rowA * ASTR + gA * 8;
    short* AsW1 = AsW0 + 32 * ASTR;

    // B staging via global_load_lds: wave covers rows wn..wn+63, 8 instrs of 8 rows.
    // LDS granule (row, g) holds global granule g ^ (row&7)  (read-side swizzle).
    const int brow = lane >> 3;                // 0..7 within 8-row group
    const int bgsw = (lane & 7) ^ brow;        // swizzled source granule
    const unsigned short* Bg = Bp + (size_t)(n0 + wn + brow) * DD + bgsw * 8;

    f32x4 acc[4][4];
    #pragma unroll
    for (int i = 0; i < 4; i++)
        #pragma unroll
        for (int j = 0; j < 4; j++) acc[i][j] = (f32x4){0.f, 0.f, 0.f, 0.f};

    // ---- prologue: issue B(0) + A(0) loads ----
    #pragma unroll
    for (int i = 0; i < 8; i++)
        gl_lds16(Bg + (size_t)(i * 8) * DD, &Bs[0][(wn + i * 8) * BK]);
    float4 a0 = *(const float4*)(Ag0);
    float4 a1 = *(const float4*)(Ag0 + 4);
    float4 a2 = *(const float4*)(Ag1);
    float4 a3 = *(const float4*)(Ag1 + 4);

    for (int kt = 0; kt < NT; kt++) {
        __syncthreads();   // prev readers of As done; drains A(kt)/B(kt) loads
        // pack + write A(kt)
        uint4 p0 = {pk2_hu(a0.x, a0.y), pk2_hu(a0.z, a0.w),
                    pk2_hu(a1.x, a1.y), pk2_hu(a1.z, a1.w)};
        uint4 p1 = {pk2_hu(a2.x, a2.y), pk2_hu(a2.z, a2.w),
                    pk2_hu(a3.x, a3.y), pk2_hu(a3.z, a3.w)};
        *(uint4*)AsW0 = p0;
        *(uint4*)AsW1 = p1;
        __syncthreads();   // As(kt) visible
        // prefetch kt+1 (in flight across the MFMA section below)
        if (kt + 1 < NT) {
            #pragma unroll
            for (int i = 0; i < 8; i++)
                gl_lds16(Bg + (size_t)(i * 8) * DD + (kt + 1) * BK,
                         &Bs[(kt + 1) & 1][(wn + i * 8) * BK]);
            a0 = *(const float4*)(Ag0 + (kt + 1) * BK);
            a1 = *(const float4*)(Ag0 + (kt + 1) * BK + 4);
            a2 = *(const float4*)(Ag1 + (kt + 1) * BK);
            a3 = *(const float4*)(Ag1 + (kt + 1) * BK + 4);
        }
        // MFMA on tile kt
        const short* Bb = Bs[kt & 1];
        #pragma unroll
        for (int s = 0; s < 2; s++) {
            bf16x8 af[4];
            #pragma unroll
            for (int mi = 0; mi < 4; mi++)
                af[mi] = *(const bf16x8*)&As[(mi * 16 + lm) * ASTR + (s * 4 + kq) * 8];
            #pragma unroll
            for (int ni = 0; ni < 4; ni++) {
                bf16x8 bf = *(const bf16x8*)
                    &Bb[(wn + ni * 16 + lm) * BK + (((s * 4 + kq)) ^ (lm & 7)) * 8];
                #pragma unroll
                for (int mi = 0; mi < 4; mi++)
                    acc[mi][ni] = __builtin_amdgcn_mfma_f32_16x16x32_bf16(
                        af[mi], bf, acc[mi][ni], 0, 0, 0);
            }
        }
    }

    // epilogue: p[mi][r] = sum over wave's 64 cols of tanh(C+base)*v
    const float* basep = base + b * HH + n0 + wn;
    const float* vp    = vw + n0 + wn;
    float p[4][4] = {};
    #pragma unroll
    for (int ni = 0; ni < 4; ni++) {
        int nl = ni * 16 + lm;
        float bs = basep[nl];
        float vv = vp[nl];
        #pragma unroll
        for (int mi = 0; mi < 4; mi++)
            #pragma unroll
            for (int r = 0; r < 4; r++)
                p[mi][r] += vv * fast_tanh(acc[mi][ni][r] + bs);
    }
    #pragma unroll
    for (int off = 8; off; off >>= 1)
        #pragma unroll
        for (int mi = 0; mi < 4; mi++)
            #pragma unroll
            for (int r = 0; r < 4; r++)
                p[mi][r] += __shfl_xor(p[mi][r], off);
    if (lm == 0) {
        #pragma unroll
        for (int mi = 0; mi < 4; mi++)
            #pragma unroll
            for (int r = 0; r < 4; r++)
                atomicAdd(&scores[m0 + mi * 16 + kq * 4 + r], p[mi][r]);
    }
}

// ---------------- softmax over S per batch -----------------------------------
__global__ __launch_bounds__(256) void k_softmax(const float* __restrict__ scores,
                                                 float* __restrict__ wout) {
    int b = blockIdx.x, tid = threadIdx.x;
    const float* rowp = scores + b * SS;
    float v[8];
    float m = -1e30f;
    #pragma unroll
    for (int i = 0; i < 8; i++) { v[i] = rowp[tid + i * 256]; m = fmaxf(m, v[i]); }
    __shared__ float sm[4], ssum[4];
    #pragma unroll
    for (int off = 32; off; off >>= 1) m = fmaxf(m, __shfl_xor(m, off));
    if ((tid & 63) == 0) sm[tid >> 6] = m;
    __syncthreads();
    m = fmaxf(fmaxf(sm[0], sm[1]), fmaxf(sm[2], sm[3]));
    float s = 0.f;
    #pragma unroll
    for (int i = 0; i < 8; i++) { v[i] = __expf(v[i] - m); s += v[i]; }
    #pragma unroll
    for (int off = 32; off; off >>= 1) s += __shfl_xor(s, off);
    if ((tid & 63) == 0) ssum[tid >> 6] = s;
    __syncthreads();
    s = ssum[0] + ssum[1] + ssum[2] + ssum[3];
    float inv = 1.f / s;
    #pragma unroll
    for (int i = 0; i < 8; i++) wout[b * SS + tid + i * 256] = v[i] * inv;
}

// ---------------- context partials (atomic-free) -----------------------------
#define CCH 64
__global__ __launch_bounds__(256) void k_ctxpart(const float* __restrict__ enc,
                                                 const float* __restrict__ w,
                                                 float* __restrict__ part) {
    int b = blockIdx.x, c = blockIdx.y, tid = threadIdx.x;
    __shared__ float wsh[CCH];
    if (tid < CCH) wsh[tid] = w[b * SS + c * CCH + tid];
    __syncthreads();
    const float4* e4 = (const float4*)(enc + ((size_t)b * SS + c * CCH) * DD);
    float4 acc = {0.f, 0.f, 0.f, 0.f};
    #pragma unroll 8
    for (int s = 0; s < CCH; s++) {
        float wv  = wsh[s];
        float4 ev = e4[(size_t)s * (DD / 4) + tid];
        acc.x += wv * ev.x; acc.y += wv * ev.y;
        acc.z += wv * ev.z; acc.w += wv * ev.w;
    }
    *(float4*)(part + (size_t)(b * 32 + c) * DD + tid * 4) = acc;
}

__global__ __launch_bounds__(256) void k_ctxreduce(const float* __restrict__ part,
                                                   float* __restrict__ ctx) {
    int b = blockIdx.x, d = blockIdx.y * 256 + threadIdx.x;
    float s = 0.f;
    #pragma unroll
    for (int c = 0; c < 32; c++) s += part[(size_t)(b * 32 + c) * DD + d];
    ctx[b * DD + d] = s;
}

extern "C" void kernel_launch(void* const* d_in, const int* in_sizes, int n_in,
                              void* d_out, int out_size, void* d_ws, size_t ws_size,
                              hipStream_t stream) {
    const float* hidden = (const float*)d_in[0];   // (L,B,D)
    const float* enc    = (const float*)d_in[1];   // (B,S,D)
    const float* attn_w = (const float*)d_in[2];   // (H,4H)
    const float* attn_b = (const float*)d_in[3];   // (H,)
    const float* v_w    = (const float*)d_in[4];   // (1,H)

    float* out      = (float*)d_out;
    float* ctx_out  = out;               // (B,1,D)
    float* attn_out = out + BB * DD;     // (B,1,S)

    float* base   = (float*)d_ws;                              // B*H
    float* scores = base + BB * HH;                            // B*S
    unsigned short* Bp = (unsigned short*)(scores + BB * SS);  // H*D bf16 (1 MB)
    float* part   = (float*)(Bp + (size_t)HH * DD);            // 32*32*D (4 MB)

    hipLaunchKernelGGL(k_zero, dim3(BB * SS / 256), dim3(256), 0, stream, scores);
    hipLaunchKernelGGL(k_pack, dim3(HH), dim3(256), 0, stream, attn_w, Bp);
    hipLaunchKernelGGL(k_base, dim3(BB * HH / 4), dim3(256), 0, stream,
                       hidden, attn_w, attn_b, base);
    hipLaunchKernelGGL(k_scores, dim3(2, BB * SS / BM), dim3(256), 0, stream,
                       enc, Bp, base, v_w, scores);
    hipLaunchKernelGGL(k_softmax, dim3(BB), dim3(256), 0, stream, scores, attn_out);
    hipLaunchKernelGGL(k_ctxpart, dim3(BB, SS / CCH), dim3(256), 0, stream,
                       enc, attn_out, part);
    hipLaunchKernelGGL(k_ctxreduce, dim3(BB, DD / 256), dim3(256), 0, stream,
                       part, ctx_out);
}